// Round 2
// baseline (1538.134 us; speedup 1.0000x reference)
//
#include <hip/hip_runtime.h>

#define VSZ   50257
#define VPAD  50304   // 393 * 128
#define BL_   2048
#define LSEQ  1024

typedef __bf16 bf16x8 __attribute__((ext_vector_type(8)));
typedef float  f32x4  __attribute__((ext_vector_type(4)));

__device__ __forceinline__ unsigned short f32_to_bf16(float f) {
  unsigned int u = __float_as_uint(f);
  u += 0x7fffu + ((u >> 16) & 1u);
  return (unsigned short)(u >> 16);
}

__device__ __forceinline__ void gload_lds16(const void* g, void* l) {
  __builtin_amdgcn_global_load_lds((const __attribute__((address_space(1))) void*)g,
                                   (__attribute__((address_space(3))) void*)l,
                                   16, 0, 0);
}

// ---------------- K0: embed fp32 -> bf16, padded to VPAD rows ----------------
__global__ __launch_bounds__(256) void convert_embed(const float* __restrict__ embed,
                                                     unsigned short* __restrict__ Eb) {
  int idx = blockIdx.x * 256 + threadIdx.x;   // float4 index
  int row = idx / 192;
  ushort4 o;
  if (row < VSZ) {
    float4 f = ((const float4*)embed)[idx];
    o.x = f32_to_bf16(f.x); o.y = f32_to_bf16(f.y);
    o.z = f32_to_bf16(f.z); o.w = f32_to_bf16(f.w);
  } else {
    o = make_ushort4(0, 0, 0, 0);
  }
  ((ushort4*)Eb)[idx] = o;
}

// ---------------- weight prep: transpose + bf16 ----------------
// WcatT[l][n][k], n in [0,256): n<128 -> W_delta[l][k][n], else W_in[l][k][n-128]
__global__ __launch_bounds__(256) void make_wcat(const float* __restrict__ Wd,
                                                 const float* __restrict__ Wi,
                                                 unsigned short* __restrict__ out) {
  int idx = blockIdx.x * 256 + threadIdx.x;   // 4*256*768
  int k = idx % 768, n = (idx / 768) & 255, l = idx / (768 * 256);
  const float* W = (n < 128) ? Wd : Wi;
  out[idx] = f32_to_bf16(W[((size_t)l * 768 + k) * 128 + (n & 127)]);
}
// WoutT[l][d][h] = W_out[l][h][d]
__global__ __launch_bounds__(256) void make_wout(const float* __restrict__ Wo,
                                                 unsigned short* __restrict__ out) {
  int idx = blockIdx.x * 256 + threadIdx.x;   // 4*768*128
  int h = idx & 127, d = (idx >> 7) % 768, l = idx / (128 * 768);
  out[idx] = f32_to_bf16(Wo[((size_t)l * 128 + h) * 768 + d]);
}

// ---------------- K1: token gather -> h [2048][768] fp32 ----------------
__global__ __launch_bounds__(256) void gather_embed(const int* __restrict__ x,
                                                    const float* __restrict__ embed,
                                                    float* __restrict__ h) {
  int idx = blockIdx.x * 256 + threadIdx.x;   // 2048*192
  int m = idx / 192, d4 = idx - m * 192;
  int tok = x[m];
  ((float4*)h)[idx] = ((const float4*)embed)[(size_t)tok * 192 + d4];
}

// ---------------- K2: depthwise causal conv (K=4) + SiLU -> u bf16 ----------------
__global__ __launch_bounds__(256) void conv_silu(const float* __restrict__ h,
                                                 const float* __restrict__ cw,  // [768][4]
                                                 const float* __restrict__ cb,  // [768]
                                                 unsigned short* __restrict__ u) {
  int idx = blockIdx.x * 256 + threadIdx.x;   // 2048*192
  int m = idx / 192, d4 = idx - m * 192;
  int b = m >> 10, l = m & 1023;
  const float4* cw4 = (const float4*)cw;
  float4 w0 = cw4[d4 * 4 + 0], w1 = cw4[d4 * 4 + 1];
  float4 w2 = cw4[d4 * 4 + 2], w3 = cw4[d4 * 4 + 3];
  float4 acc = ((const float4*)cb)[d4];
  #pragma unroll
  for (int j = 0; j < 4; ++j) {
    int lj = l + j - 3;
    if (lj >= 0) {
      float4 xv = ((const float4*)h)[(size_t)((b << 10) + lj) * 192 + d4];
      acc.x += xv.x * (&w0.x)[j];
      acc.y += xv.y * (&w1.x)[j];
      acc.z += xv.z * (&w2.x)[j];
      acc.w += xv.w * (&w3.x)[j];
    }
  }
  acc.x = acc.x / (1.f + expf(-acc.x));
  acc.y = acc.y / (1.f + expf(-acc.y));
  acc.z = acc.z / (1.f + expf(-acc.z));
  acc.w = acc.w / (1.f + expf(-acc.w));
  ushort4 o;
  o.x = f32_to_bf16(acc.x); o.y = f32_to_bf16(acc.y);
  o.z = f32_to_bf16(acc.z); o.w = f32_to_bf16(acc.w);
  ((ushort4*)u)[idx] = o;
}

// ---------------- generic MFMA bf16 GEMM, 128x128 tile, BK=64, XOR-swizzled LDS ----
// C[m][n] = A[m][:KTOT] . B[n][:KTOT]   (B in B^T layout, row stride KTOT)
// MODE 0: store fp32   MODE 1: C += acc   MODE 2: nontemporal store, col<VSZ guard
template<int KTOT, int MODE>
__global__ __launch_bounds__(256) void gemm_mfma(const unsigned short* __restrict__ A,
                                                 const unsigned short* __restrict__ Bm,
                                                 float* __restrict__ C, int ldc) {
  __shared__ unsigned short As[128 * 64];
  __shared__ unsigned short Bs[128 * 64];
  const int m0 = blockIdx.x * 128;
  const int n0 = blockIdx.y * 128;
  const int tid = threadIdx.x;
  const int lane = tid & 63;
  const int wave = tid >> 6;
  const int wm = (wave & 1) * 64;
  const int wn = (wave >> 1) * 64;
  const int lrow = lane >> 3;                  // 0..7
  const int lcol = ((lane & 7) ^ lrow) * 8;    // XOR-swizzled source column chunk

  f32x4 acc[4][4];
  #pragma unroll
  for (int i = 0; i < 4; ++i)
    #pragma unroll
    for (int j = 0; j < 4; ++j)
      acc[i][j] = f32x4{0.f, 0.f, 0.f, 0.f};

  for (int k0 = 0; k0 < KTOT; k0 += 64) {
    #pragma unroll
    for (int inst = 0; inst < 4; ++inst) {
      int c = wave * 4 + inst;       // 16 chunks, each 8 rows x 64 cols
      int r = c * 8 + lrow;
      gload_lds16(A  + (size_t)(m0 + r) * KTOT + k0 + lcol, &As[c * 512]);
      gload_lds16(Bm + (size_t)(n0 + r) * KTOT + k0 + lcol, &Bs[c * 512]);
    }
    __syncthreads();
    #pragma unroll
    for (int kk = 0; kk < 64; kk += 32) {
      bf16x8 af[4], bfr[4];
      const int frow = lane & 15;
      const int quad = lane >> 4;
      const int fx = lane & 7;                 // == row & 7 for fragment rows
      const int cb = quad + (kk >> 3);         // logical 8-elem column chunk
      const int physc = (cb ^ fx) * 8;         // swizzled element offset
      #pragma unroll
      for (int i = 0; i < 4; ++i)
        af[i] = *(const bf16x8*)(&As[(wm + frow + i * 16) * 64 + physc]);
      #pragma unroll
      for (int j = 0; j < 4; ++j)
        bfr[j] = *(const bf16x8*)(&Bs[(wn + frow + j * 16) * 64 + physc]);
      #pragma unroll
      for (int i = 0; i < 4; ++i)
        #pragma unroll
        for (int j = 0; j < 4; ++j)
          acc[i][j] = __builtin_amdgcn_mfma_f32_16x16x32_bf16(af[i], bfr[j], acc[i][j], 0, 0, 0);
    }
    __syncthreads();
  }

  const int cr = (lane >> 4) * 4;   // C/D: col = lane&15, row = (lane>>4)*4 + reg
  const int cc = lane & 15;
  #pragma unroll
  for (int i = 0; i < 4; ++i) {
    #pragma unroll
    for (int j = 0; j < 4; ++j) {
      int gc = n0 + wn + j * 16 + cc;
      if (MODE == 2 && gc >= VSZ) continue;
      size_t base = (size_t)(m0 + wm + i * 16 + cr) * ldc + gc;
      #pragma unroll
      for (int r = 0; r < 4; ++r) {
        float v = acc[i][j][r];
        if (MODE == 0)      C[base + (size_t)r * ldc] = v;
        else if (MODE == 1) C[base + (size_t)r * ldc] += v;
        else                __builtin_nontemporal_store(v, &C[base + (size_t)r * ldc]);
      }
    }
  }
}

// ---------------- fused chunked scan: pre fp32 -> hs bf16 ----------------
__device__ __forceinline__ void dz_at(const float* __restrict__ pre, float bdv, float negA,
                                      int m, int hh, float& d, float& z) {
  float pd = pre[(size_t)m * 256 + hh];
  float bu = pre[(size_t)m * 256 + 128 + hh];
  float xx = pd + bdv;
  float delta = (xx > 20.f) ? xx : log1pf(expf(xx));
  d = expf(delta * negA);
  z = delta * bu;
}

// grid (2,2): x = batch, y = hh half; block 1024 = 16 chunks x 64 hh, 64 steps/chunk
__global__ __launch_bounds__(1024) void scan_fused(const float* __restrict__ pre,
                                                   const float* __restrict__ bd,
                                                   const float* __restrict__ logA,
                                                   unsigned short* __restrict__ hsb) {
  __shared__ float sP[16][64], sQ[16][64], sS[16][64];
  const int hl = threadIdx.x & 63;
  const int c  = threadIdx.x >> 6;     // 0..15
  const int b  = blockIdx.x;
  const int hh = blockIdx.y * 64 + hl;
  const float bdv = bd[hh];
  const float negA = -expf(logA[hh]);
  const int mbase = b * LSEQ + c * 64;

  float P = 1.f, Q = 0.f;
  for (int s = 0; s < 64; ++s) {
    float d, z;
    dz_at(pre, bdv, negA, mbase + s, hh, d, z);
    Q = d * Q + z;
    P *= d;
  }
  sP[c][hl] = P; sQ[c][hl] = Q;
  __syncthreads();
  if (c == 0) {
    float s = 0.f;
    #pragma unroll
    for (int cc2 = 0; cc2 < 16; ++cc2) {
      sS[cc2][hl] = s;
      s = sP[cc2][hl] * s + sQ[cc2][hl];
    }
  }
  __syncthreads();
  float s = sS[c][hl];
  for (int st = 0; st < 64; ++st) {
    float d, z;
    dz_at(pre, bdv, negA, mbase + st, hh, d, z);
    s = d * s + z;
    hsb[(size_t)(mbase + st) * 128 + hh] = f32_to_bf16(s);
  }
}

// ---------------- LayerNorm -> bf16 ----------------
__global__ __launch_bounds__(256) void ln_bf16(const float* __restrict__ h,
                                               const float* __restrict__ gamma,
                                               const float* __restrict__ beta,
                                               unsigned short* __restrict__ hnb) {
  __shared__ float red[10];
  int m = blockIdx.x;
  const float* row = h + (size_t)m * 768;
  int tid = threadIdx.x;
  float a0 = row[tid], a1 = row[tid + 256], a2 = row[tid + 512];
  float s = a0 + a1 + a2;
  float s2 = a0 * a0 + a1 * a1 + a2 * a2;
  #pragma unroll
  for (int o = 32; o > 0; o >>= 1) { s += __shfl_down(s, o); s2 += __shfl_down(s2, o); }
  int wv = tid >> 6;
  if ((tid & 63) == 0) { red[wv] = s; red[4 + wv] = s2; }
  __syncthreads();
  if (tid == 0) {
    float S = red[0] + red[1] + red[2] + red[3];
    float S2 = red[4] + red[5] + red[6] + red[7];
    float mu = S * (1.f / 768.f);
    float var = S2 * (1.f / 768.f) - mu * mu;
    red[8] = mu;
    red[9] = rsqrtf(var + 1e-5f);
  }
  __syncthreads();
  float mu = red[8], rs = red[9];
  unsigned short* orow = hnb + (size_t)m * 768;
  orow[tid]       = f32_to_bf16((a0 - mu) * rs * gamma[tid]       + beta[tid]);
  orow[tid + 256] = f32_to_bf16((a1 - mu) * rs * gamma[tid + 256] + beta[tid + 256]);
  orow[tid + 512] = f32_to_bf16((a2 - mu) * rs * gamma[tid + 512] + beta[tid + 512]);
}

// ---------------- launch ----------------
extern "C" void kernel_launch(void* const* d_in, const int* in_sizes, int n_in,
                              void* d_out, int out_size, void* d_ws, size_t ws_size,
                              hipStream_t stream) {
  (void)in_sizes; (void)n_in; (void)out_size; (void)ws_size;
  const int*   x       = (const int*)d_in[0];
  const float* embed   = (const float*)d_in[1];
  const float* conv_w  = (const float*)d_in[2];
  const float* conv_b  = (const float*)d_in[3];
  const float* W_delta = (const float*)d_in[4];
  const float* b_delta = (const float*)d_in[5];
  const float* W_in    = (const float*)d_in[6];
  const float* W_out   = (const float*)d_in[7];
  const float* log_A   = (const float*)d_in[8];
  const float* gamma   = (const float*)d_in[9];
  const float* beta    = (const float*)d_in[10];
  float* out = (float*)d_out;

  char* wsp = (char*)d_ws;
  size_t off = 0;
  auto carve = [&](size_t bytes) -> char* {
    char* p = wsp + off;
    off += (bytes + 255) & ~(size_t)255;
    return p;
  };
  unsigned short* Eb    = (unsigned short*)carve((size_t)VPAD * 768 * 2);   // 77.3 MB
  unsigned short* WcatT = (unsigned short*)carve((size_t)4 * 256 * 768 * 2);
  unsigned short* WoutT = (unsigned short*)carve((size_t)4 * 768 * 128 * 2);
  float*          h     = (float*)carve((size_t)BL_ * 768 * 4);
  unsigned short* u     = (unsigned short*)carve((size_t)BL_ * 768 * 2);
  float*          pre   = (float*)carve((size_t)BL_ * 256 * 4);
  unsigned short* hs    = (unsigned short*)carve((size_t)BL_ * 128 * 2);
  unsigned short* hnb   = (unsigned short*)carve((size_t)BL_ * 768 * 2);

  convert_embed<<<(VPAD * 192) / 256, 256, 0, stream>>>(embed, Eb);
  make_wcat<<<(4 * 256 * 768) / 256, 256, 0, stream>>>(W_delta, W_in, WcatT);
  make_wout<<<(4 * 768 * 128) / 256, 256, 0, stream>>>(W_out, WoutT);
  gather_embed<<<(BL_ * 192) / 256, 256, 0, stream>>>(x, embed, h);

  for (int i = 0; i < 4; ++i) {
    conv_silu<<<(BL_ * 192) / 256, 256, 0, stream>>>(h, conv_w + (size_t)i * 768 * 4,
                                                     conv_b + (size_t)i * 768, u);
    gemm_mfma<768, 0><<<dim3(16, 2), 256, 0, stream>>>(u, WcatT + (size_t)i * 256 * 768,
                                                       pre, 256);
    scan_fused<<<dim3(2, 2), 1024, 0, stream>>>(pre, b_delta + i * 128, log_A + i * 128, hs);
    gemm_mfma<128, 1><<<dim3(16, 6), 256, 0, stream>>>(hs, WoutT + (size_t)i * 768 * 128,
                                                       h, 768);
  }

  ln_bf16<<<BL_, 256, 0, stream>>>(h, gamma, beta, hnb);
  gemm_mfma<768, 2><<<dim3(16, 393), 256, 0, stream>>>(hnb, Eb, out, VSZ);
}